// Round 6
// baseline (86.579 us; speedup 1.0000x reference)
//
#include <hip/hip_runtime.h>

// Problem: N=4096 rows, D=64 feats, 10 classes.
// sym KL: sym_ij = 0.25*(H_i . Hp_j + s_i + s_j + det_ij + det_ji - 128)
// per-feature packed K layout (K=256):
//   H[r][4d+{0,1,2,3}] = { var+mu^2, -2mu, 1/var, mu/var }   (F0,F1,G0,G1)
// Hp (the {G0,G1,F0,F1} order) is NOT stored: Hp[e] = H[pi(e)] where pi swaps
// components c<->c+2 within each 4-group; pi is an involution, so
//   sum_e H_i[e]*Hp_j[e] = sum_e H_i[e]*H_j[pi(e)]
// and pi on a lane's 8-element fragment is a 32-bit register permutation
// [v1,v0,v3,v2] -- done in-register, no second array.
//
// Storage is MFMA-FRAGMENT-MAJOR: Hf[tile=r>>5][k=e>>4][(r&31)*16 + (e&15)]
// so each (row-tile, k) fragment is a 1 KB contiguous chunk -- exactly the
// wave-uniform-base + lane*16 contract of global_load_lds, and a perfect
// 1 KB partition for conflict-free ds_read_b128 on the consume side.
//
// R11 vs R5/R10: K-loop sourced from LDS via global_load_lds double-buffer.
// Evidence trail: R7 VGPR=68 / R9 VGPR=64 proved hipcc sinks register
// prefetch to just-before-use (R8/R9/R10 all neutral-or-worse); per-delta
// inference puts pair at ~20-28 us vs ~4 us L2-BW floor, stall-bound on
// un-overlapped L2 latency (MfmaUtil 3%, VALU 8%, HBM 2%). Fix is the
// guide's T3-minimum 2-phase: stage quarter q+1 (32 KB: 2 panels x 4
// row-tiles x 4 k-frags) into buf^1 BEFORE computing quarter q from buf;
// __syncthreads()'s vmcnt(0)+barrier is exactly the phase-end wait. LDS
// 64 KB staging + 4 KB stats -> still 2 blocks/CU. Grid/epilogue/reduction
// = R5 verbatim (proven 78.1 us structure).

#define N 4096
#define D 64
#define KH 256
#define MT 128             // pair block tile side
#define TILES2 32          // 4096/128
#define NBLK2 528          // TILES2*(TILES2+1)/2 upper-tri blocks
#define DET_EPS 1e-8f

typedef short bf16x8 __attribute__((ext_vector_type(8)));
typedef float f32x16 __attribute__((ext_vector_type(16)));

// ws byte layout
#define WS_H    0                       // ushort[N/32][16][512] = 2 MB (frag-major)
#define WS_PSL  (N * KH * 2)            // float4[N] = 64 KB
#define WS_PART (WS_PSL + N * 16)       // float[2*NBLK2]

static __device__ __forceinline__ unsigned short f2bf(float x) {
  // round-to-nearest-even bf16
  unsigned int u = __float_as_uint(x);
  unsigned int r = (u + 0x7FFFu + ((u >> 16) & 1u)) >> 16;
  return (unsigned short)r;
}

static __device__ __forceinline__ f32x16 mfma_bf16(bf16x8 a, bf16x8 b, f32x16 c) {
  return __builtin_amdgcn_mfma_f32_32x32x16_bf16(a, b, c, 0, 0, 0);
}

// async global->LDS, 16 B per lane; LDS dest = uniform base + lane*16 (HW).
static __device__ __forceinline__ void glds16(const unsigned short* g,
                                              unsigned short* l) {
  __builtin_amdgcn_global_load_lds(
      (const __attribute__((address_space(1))) unsigned int*)g,
      (__attribute__((address_space(3))) unsigned int*)l, 16, 0, 0);
}

// ---------------------------------------------------------------------------
// Kernel 1: per-row precompute. 1024 blocks x 256 thr; one wave per row.
// Stores Hf (frag-major) and PSL = {p, 1/(p+eps), 0.25*s-16, label}.
__global__ __launch_bounds__(256) void precompute_kernel(
    const float* __restrict__ mu, const float* __restrict__ var,
    const int* __restrict__ labels,
    unsigned short* __restrict__ Hf, float4* __restrict__ PSL) {
  const int t = threadIdx.x;
  const int lane = t & 63;   // feature d
  const int w = t >> 6;
  const int r = blockIdx.x * 4 + w;

  const float m = mu[r * D + lane];
  const float v = var[r * D + lane];
  const float g0 = 1.0f / v;
  const float f0 = v + m * m;
  const float f1 = -2.0f * m;
  const float g1 = m * g0;

  // element e = 4*d + c; frag-major idx:
  //   (r>>5)*8192 + (e>>4)*512 + (r&31)*16 + (e&15)
  // lane d writes e = 4d..4d+3 -> 4 contiguous ushorts.
  const size_t base = (size_t)(r >> 5) * 8192 + (size_t)(lane >> 2) * 512
                      + (size_t)(r & 31) * 16 + (size_t)(lane & 3) * 4;
  *(ushort4*)&Hf[base] = make_ushort4(f2bf(f0), f2bf(f1), f2bf(g0), f2bf(g1));

  // wave reductions: p = prod var, s = sum mu^2/var
  float p = v;
  float s = m * m * g0;
  #pragma unroll
  for (int off = 1; off < 64; off <<= 1) {
    p *= __shfl_xor(p, off);
    s += __shfl_xor(s, off);
  }
  if (lane == 0) {
    PSL[r] = make_float4(p, 1.0f / (p + DET_EPS), 0.25f * s - 16.0f,
                         (float)labels[r]);
  }
}

// ---------------------------------------------------------------------------
// Kernel 2: upper-tri 128x128 pair tiles. 4 waves; wave w = quadrant
// (sr=w>>1, sc=w&1), each wave computes a 2x2 grid of 32x32 MFMA subtiles.
// B fragments derived from H via in-register component swap (see header).
// K staged through LDS: 4 quarters, double-buffered, global_load_lds direct.
__global__ __launch_bounds__(256, 2) void pair_kernel(
    const unsigned short* __restrict__ Hf,
    const float4* __restrict__ PSL, float* __restrict__ partial) {
  // [buf][panel(A/B)][row-tile 0..3][k-frag 0..3][512] : 64 KB
  __shared__ unsigned short sH[2][2][4][4][512];
  __shared__ float4 sPi[128];
  __shared__ float4 sPj[128];
  __shared__ float red[8];

  // triangular decode: block L -> (it, jt), it <= jt  (32x32 tile grid)
  int L = (int)blockIdx.x;
  int it = (int)(32.5f - sqrtf(32.5f * 32.5f - 2.0f * (float)L));
  while (it > 0 && L < it * TILES2 - it * (it - 1) / 2) --it;
  while (L >= (it + 1) * TILES2 - (it + 1) * it / 2) ++it;
  const int jt = it + (L - (it * TILES2 - it * (it - 1) / 2));
  const int i0 = it * MT, j0 = jt * MT;

  const int t = threadIdx.x;
  const int lane = t & 63;
  const int w = t >> 6;               // 0..3
  const int sr = w >> 1, sc = w & 1;  // 64x64 quadrant of the 128x128 block
  const int at0 = i0 >> 5, bt0 = j0 >> 5;  // panel base row-tiles in Hf

  // stage per-row stats {p, 1/(p+eps), 0.25*s-16, label}
  if (t < 128) sPi[t] = PSL[i0 + t];
  else sPj[t - 128] = PSL[j0 + t - 128];

  // stage quarter q (32 x 1KB chunks) into sH[buf]; wave w takes chunks
  // w*8..w*8+7. Chunk cid -> (panel p, row-tile rt, k-frag kk).
#define STAGE(buf, q)                                                       \
  {                                                                         \
    _Pragma("unroll")                                                       \
    for (int u = 0; u < 8; ++u) {                                           \
      const int cid = w * 8 + u;                                            \
      const int p = cid >> 4, rt = (cid >> 2) & 3, kk = cid & 3;            \
      const unsigned short* g = Hf                                          \
          + (size_t)((p ? bt0 : at0) + rt) * 8192 + ((q) * 4 + kk) * 512    \
          + lane * 8;                                                       \
      glds16(g, &sH[buf][p][rt][kk][0]);                                    \
    }                                                                       \
  }

  STAGE(0, 0);
  __syncthreads();   // vmcnt(0)+barrier: buf0 ready, sPi/sPj ready

  const int l31 = lane & 31;
  const int slot = l31 * 16 + (lane >> 5) * 8;  // frag-major lane slot

  // diagonal big-tile: quadrant (1,0) is entirely below the diagonal
  const bool active = !(it == jt && w == 2);

  f32x16 C00 = {}, C01 = {}, C10 = {}, C11 = {};
  float pos = 0.0f, neg = 0.0f;

  #pragma unroll
  for (int q = 0; q < 4; ++q) {
    const int cb = q & 1;
    if (q < 3) STAGE(cb ^ 1, q + 1);  // issue next quarter before compute
    if (active) {
      #pragma unroll
      for (int kk = 0; kk < 4; ++kk) {
        const bf16x8 a0 = *(const bf16x8*)&sH[cb][0][2 * sr + 0][kk][slot];
        const bf16x8 a1 = *(const bf16x8*)&sH[cb][0][2 * sr + 1][kk][slot];
        const bf16x8 c0 = *(const bf16x8*)&sH[cb][1][2 * sc + 0][kk][slot];
        const bf16x8 c1 = *(const bf16x8*)&sH[cb][1][2 * sc + 1][kk][slot];
        // pi(e): swap component pairs -> 32-bit reg perm [v1,v0,v3,v2]
        const bf16x8 b0 = __builtin_shufflevector(c0, c0, 2, 3, 0, 1, 6, 7, 4, 5);
        const bf16x8 b1 = __builtin_shufflevector(c1, c1, 2, 3, 0, 1, 6, 7, 4, 5);
        C00 = mfma_bf16(a0, b0, C00);
        C01 = mfma_bf16(a0, b1, C01);
        C10 = mfma_bf16(a1, b0, C10);
        C11 = mfma_bf16(a1, b1, C11);
      }
    }
    __syncthreads();  // drains this iter's STAGE (hidden under compute) +
                      // protects buf reuse next iter
  }
#undef STAGE

  if (active) {
    // epilogue: C/D layout col=lane&31, row=(r&3)+8*(r>>2)+4*(lane>>5)
    const int rbase = 4 * (lane >> 5);
    #pragma unroll
    for (int mn = 0; mn < 4; ++mn) {
      const int m = mn >> 1, n = mn & 1;
      const f32x16 C = (mn == 0) ? C00 : (mn == 1) ? C01 : (mn == 2) ? C10 : C11;
      const int jloc = (sc * 2 + n) * 32 + l31;
      const int j = j0 + jloc;
      const float4 pj = sPj[jloc];
      #pragma unroll
      for (int r = 0; r < 16; ++r) {
        const int row = (r & 3) + 8 * (r >> 2) + rbase;
        const int iloc = (sr * 2 + m) * 32 + row;
        const int i = i0 + iloc;
        if (i < j) {                   // strict upper triangle only
          const float4 pi = sPi[iloc];
          const float det = pj.x * pi.y + pi.x * pj.y;
          const float sym = 0.25f * (C[r] + det) + pi.z + pj.z;
          const float sig = __builtin_amdgcn_rcpf(1.0f + __expf(-sym));
          if (pi.w == pj.w) pos += sig; else neg += sig;
        }
      }
    }
  }

  // wave reduce -> LDS -> per-block private slot store (no atomics)
  #pragma unroll
  for (int off = 32; off > 0; off >>= 1) {
    pos += __shfl_down(pos, off);
    neg += __shfl_down(neg, off);
  }
  if (lane == 0) { red[w] = pos; red[4 + w] = neg; }
  __syncthreads();
  if (t == 0) {
    partial[L]         = red[0] + red[1] + red[2] + red[3];
    partial[NBLK2 + L] = red[4] + red[5] + red[6] + red[7];
  }
}

// ---------------------------------------------------------------------------
// Kernel 3: reduce per-block slots, finalize 4 outputs.
// Full-grid sums = 2 * triangle sums (sym matrix, diag excluded).
__global__ __launch_bounds__(256) void finalize_kernel(
    const float* __restrict__ partial, float* __restrict__ out) {
  __shared__ float redp[4], redn[4];
  const int t = threadIdx.x;
  const int lane = t & 63, w = t >> 6;
  float p = 0.0f, n = 0.0f;
  for (int i = t; i < NBLK2; i += 256) {
    p += partial[i];
    n += partial[NBLK2 + i];
  }
  #pragma unroll
  for (int off = 32; off > 0; off >>= 1) {
    p += __shfl_down(p, off);
    n += __shfl_down(n, off);
  }
  if (lane == 0) { redp[w] = p; redn[w] = n; }
  __syncthreads();
  if (t == 0) {
    const float pos = 2.0f * (redp[0] + redp[1] + redp[2] + redp[3]);
    const float neg = 2.0f * (redn[0] + redn[1] + redn[2] + redn[3]);
    out[0] = pos * (1.0f / 16777216.0f);  // mean over N*N = 2^24
    out[1] = neg * (1.0f / 16777216.0f);
    out[2] = pos;
    out[3] = neg;
  }
}

extern "C" void kernel_launch(void* const* d_in, const int* in_sizes, int n_in,
                              void* d_out, int out_size, void* d_ws, size_t ws_size,
                              hipStream_t stream) {
  const float* mu = (const float*)d_in[0];
  const float* var = (const float*)d_in[1];
  const int* labels = (const int*)d_in[2];
  float* out = (float*)d_out;
  char* ws = (char*)d_ws;

  unsigned short* Hf = (unsigned short*)(ws + WS_H);
  float4* PSL = (float4*)(ws + WS_PSL);
  float* partial = (float*)(ws + WS_PART);

  precompute_kernel<<<dim3(N / 4), dim3(256), 0, stream>>>(mu, var, labels, Hf, PSL);
  pair_kernel<<<dim3(NBLK2), dim3(256), 0, stream>>>(Hf, PSL, partial);
  finalize_kernel<<<dim3(1), dim3(256), 0, stream>>>(partial, out);
}

// Round 7
// 79.269 us; speedup vs baseline: 1.0922x; 1.0922x over previous
//
#include <hip/hip_runtime.h>

// Problem: N=4096 rows, D=64 feats, 10 classes.
// sym KL: sym_ij = 0.25*(H_i . Hp_j + s_i + s_j + det_ij + det_ji - 128)
// per-feature packed K layout (K=256):
//   H[r][4d+{0,1,2,3}] = { var+mu^2, -2mu, 1/var, mu/var }   (F0,F1,G0,G1)
// Hp (the {G0,G1,F0,F1} order) is NOT stored: Hp[e] = H[pi(e)] where pi swaps
// components c<->c+2 within each 4-group; pi is an involution, so
//   sum_e H_i[e]*Hp_j[e] = sum_e H_i[e]*H_j[pi(e)]
// and pi on a lane's 8-element fragment is a 32-bit register permutation
// [v1,v0,v3,v2] -- done in-register, no second array.
//
// Storage is MFMA-FRAGMENT-MAJOR: Hf[tile=r>>5][k=e>>4][(r&31)*16 + (e&15)]
// so each k-step fragment load is 64 lanes x 16 B = 1 KB contiguous.
//
// FINAL (R12) = R5 verbatim, the session's best measured kernel (78.08 us).
// Session ledger of rejected alternatives (all measured on MI355X):
//   R6  cooperative grid.sync fusion      -> 207.8 us (grid sync ~135 us spin)
//   R7  last-block device-scope protocol  -> 107.7 us (512 serialized
//       cross-XCD RMWs + fences ~42 us -- never put a device-scope
//       rendezvous on a ~10 us critical path)
//   R8  reg-prefetch arrays + balanced grid -> 83.9 us
//   R9  64x64 1-wave blocks               -> 90.4 us
//   R10 fenced chunked prefetch           -> 78.8 us (neutral; hipcc sinks
//       register prefetch regardless -- VGPR stayed ~64-68 across variants)
//   R11 global_load_lds LDS double-buffer -> 86.6 us (vmcnt(0) barrier drain)
// Conclusion: pair_kernel is ~7-10 us, near its L2 floor at the grid-limited
// 2.06 blocks/CU; the timed window is dominated by the harness's 256 MB
// workspace re-poison fill (41.4 us @ ~81% HBM peak) + reset memsets +
// replay overhead (~55-60 us fixed). No controllable headroom beyond noise.

#define N 4096
#define D 64
#define KH 256
#define MT 128             // pair block tile side
#define TILES2 32          // 4096/128
#define NBLK2 528          // TILES2*(TILES2+1)/2 upper-tri blocks
#define DET_EPS 1e-8f

typedef short bf16x8 __attribute__((ext_vector_type(8)));
typedef float f32x16 __attribute__((ext_vector_type(16)));

// ws byte layout
#define WS_H    0                       // ushort[N/32][16][512] = 2 MB (frag-major)
#define WS_PSL  (N * KH * 2)            // float4[N] = 64 KB
#define WS_PART (WS_PSL + N * 16)       // float[2*NBLK2]

static __device__ __forceinline__ unsigned short f2bf(float x) {
  // round-to-nearest-even bf16
  unsigned int u = __float_as_uint(x);
  unsigned int r = (u + 0x7FFFu + ((u >> 16) & 1u)) >> 16;
  return (unsigned short)r;
}

static __device__ __forceinline__ f32x16 mfma_bf16(bf16x8 a, bf16x8 b, f32x16 c) {
  return __builtin_amdgcn_mfma_f32_32x32x16_bf16(a, b, c, 0, 0, 0);
}

// ---------------------------------------------------------------------------
// Kernel 1: per-row precompute. 1024 blocks x 256 thr; one wave per row.
// Stores Hf (frag-major) and PSL = {p, 1/(p+eps), 0.25*s-16, label}.
__global__ __launch_bounds__(256) void precompute_kernel(
    const float* __restrict__ mu, const float* __restrict__ var,
    const int* __restrict__ labels,
    unsigned short* __restrict__ Hf, float4* __restrict__ PSL) {
  const int t = threadIdx.x;
  const int lane = t & 63;   // feature d
  const int w = t >> 6;
  const int r = blockIdx.x * 4 + w;

  const float m = mu[r * D + lane];
  const float v = var[r * D + lane];
  const float g0 = 1.0f / v;
  const float f0 = v + m * m;
  const float f1 = -2.0f * m;
  const float g1 = m * g0;

  // element e = 4*d + c; frag-major idx:
  //   (r>>5)*8192 + (e>>4)*512 + (r&31)*16 + (e&15)
  // lane d writes e = 4d..4d+3 -> 4 contiguous ushorts.
  const size_t base = (size_t)(r >> 5) * 8192 + (size_t)(lane >> 2) * 512
                      + (size_t)(r & 31) * 16 + (size_t)(lane & 3) * 4;
  *(ushort4*)&Hf[base] = make_ushort4(f2bf(f0), f2bf(f1), f2bf(g0), f2bf(g1));

  // wave reductions: p = prod var, s = sum mu^2/var
  float p = v;
  float s = m * m * g0;
  #pragma unroll
  for (int off = 1; off < 64; off <<= 1) {
    p *= __shfl_xor(p, off);
    s += __shfl_xor(s, off);
  }
  if (lane == 0) {
    PSL[r] = make_float4(p, 1.0f / (p + DET_EPS), 0.25f * s - 16.0f,
                         (float)labels[r]);
  }
}

// ---------------------------------------------------------------------------
// Kernel 2: upper-tri 128x128 pair tiles. 4 waves; wave w = quadrant
// (sr=w>>1, sc=w&1), each wave computes a 2x2 grid of 32x32 MFMA subtiles.
// B fragments derived from H via in-register component swap (see header).
__global__ __launch_bounds__(256, 2) void pair_kernel(
    const unsigned short* __restrict__ Hf,
    const float4* __restrict__ PSL, float* __restrict__ partial) {
  __shared__ float4 sPi[128];
  __shared__ float4 sPj[128];
  __shared__ float red[8];

  // triangular decode: block L -> (it, jt), it <= jt  (32x32 tile grid)
  int L = (int)blockIdx.x;
  int it = (int)(32.5f - sqrtf(32.5f * 32.5f - 2.0f * (float)L));
  while (it > 0 && L < it * TILES2 - it * (it - 1) / 2) --it;
  while (L >= (it + 1) * TILES2 - (it + 1) * it / 2) ++it;
  const int jt = it + (L - (it * TILES2 - it * (it - 1) / 2));
  const int i0 = it * MT, j0 = jt * MT;

  const int t = threadIdx.x;
  const int lane = t & 63;
  const int w = t >> 6;               // 0..3
  const int sr = w >> 1, sc = w & 1;  // 64x64 quadrant of the 128x128 block

  // stage per-row stats {p, 1/(p+eps), 0.25*s-16, label}
  if (t < 128) sPi[t] = PSL[i0 + t];
  else sPj[t - 128] = PSL[j0 + t - 128];
  __syncthreads();

  const int l31 = lane & 31;
  const int slot = l31 * 16 + (lane >> 5) * 8;  // frag-major lane slot
  const unsigned short* pa = Hf + (size_t)(i0 / 32 + sr * 2) * 8192 + slot;
  const unsigned short* pb = Hf + (size_t)(j0 / 32 + sc * 2) * 8192 + slot;

  // diagonal big-tile: quadrant (1,0) is entirely below the diagonal
  const bool active = !(it == jt && w == 2);

  f32x16 C00 = {}, C01 = {}, C10 = {}, C11 = {};
  float pos = 0.0f, neg = 0.0f;

  if (active) {
    #pragma unroll 4
    for (int k = 0; k < 16; ++k) {
      const bf16x8 a0 = *(const bf16x8*)(pa + k * 512);
      const bf16x8 a1 = *(const bf16x8*)(pa + 8192 + k * 512);
      const bf16x8 c0 = *(const bf16x8*)(pb + k * 512);
      const bf16x8 c1 = *(const bf16x8*)(pb + 8192 + k * 512);
      // pi(e): swap component pairs -> 32-bit reg perm [v1,v0,v3,v2]
      const bf16x8 b0 = __builtin_shufflevector(c0, c0, 2, 3, 0, 1, 6, 7, 4, 5);
      const bf16x8 b1 = __builtin_shufflevector(c1, c1, 2, 3, 0, 1, 6, 7, 4, 5);
      C00 = mfma_bf16(a0, b0, C00);
      C01 = mfma_bf16(a0, b1, C01);
      C10 = mfma_bf16(a1, b0, C10);
      C11 = mfma_bf16(a1, b1, C11);
    }

    // epilogue: C/D layout col=lane&31, row=(r&3)+8*(r>>2)+4*(lane>>5)
    const int rbase = 4 * (lane >> 5);
    #pragma unroll
    for (int mn = 0; mn < 4; ++mn) {
      const int m = mn >> 1, n = mn & 1;
      const f32x16 C = (mn == 0) ? C00 : (mn == 1) ? C01 : (mn == 2) ? C10 : C11;
      const int jloc = (sc * 2 + n) * 32 + l31;
      const int j = j0 + jloc;
      const float4 pj = sPj[jloc];
      #pragma unroll
      for (int r = 0; r < 16; ++r) {
        const int row = (r & 3) + 8 * (r >> 2) + rbase;
        const int iloc = (sr * 2 + m) * 32 + row;
        const int i = i0 + iloc;
        if (i < j) {                   // strict upper triangle only
          const float4 pi = sPi[iloc];
          const float det = pj.x * pi.y + pi.x * pj.y;
          const float sym = 0.25f * (C[r] + det) + pi.z + pj.z;
          const float sig = __builtin_amdgcn_rcpf(1.0f + __expf(-sym));
          if (pi.w == pj.w) pos += sig; else neg += sig;
        }
      }
    }
  }

  // wave reduce -> LDS -> per-block private slot store (no atomics)
  #pragma unroll
  for (int off = 32; off > 0; off >>= 1) {
    pos += __shfl_down(pos, off);
    neg += __shfl_down(neg, off);
  }
  if (lane == 0) { red[w] = pos; red[4 + w] = neg; }
  __syncthreads();
  if (t == 0) {
    partial[L]         = red[0] + red[1] + red[2] + red[3];
    partial[NBLK2 + L] = red[4] + red[5] + red[6] + red[7];
  }
}

// ---------------------------------------------------------------------------
// Kernel 3: reduce per-block slots, finalize 4 outputs.
// Full-grid sums = 2 * triangle sums (sym matrix, diag excluded).
__global__ __launch_bounds__(256) void finalize_kernel(
    const float* __restrict__ partial, float* __restrict__ out) {
  __shared__ float redp[4], redn[4];
  const int t = threadIdx.x;
  const int lane = t & 63, w = t >> 6;
  float p = 0.0f, n = 0.0f;
  for (int i = t; i < NBLK2; i += 256) {
    p += partial[i];
    n += partial[NBLK2 + i];
  }
  #pragma unroll
  for (int off = 32; off > 0; off >>= 1) {
    p += __shfl_down(p, off);
    n += __shfl_down(n, off);
  }
  if (lane == 0) { redp[w] = p; redn[w] = n; }
  __syncthreads();
  if (t == 0) {
    const float pos = 2.0f * (redp[0] + redp[1] + redp[2] + redp[3]);
    const float neg = 2.0f * (redn[0] + redn[1] + redn[2] + redn[3]);
    out[0] = pos * (1.0f / 16777216.0f);  // mean over N*N = 2^24
    out[1] = neg * (1.0f / 16777216.0f);
    out[2] = pos;
    out[3] = neg;
  }
}

extern "C" void kernel_launch(void* const* d_in, const int* in_sizes, int n_in,
                              void* d_out, int out_size, void* d_ws, size_t ws_size,
                              hipStream_t stream) {
  const float* mu = (const float*)d_in[0];
  const float* var = (const float*)d_in[1];
  const int* labels = (const int*)d_in[2];
  float* out = (float*)d_out;
  char* ws = (char*)d_ws;

  unsigned short* Hf = (unsigned short*)(ws + WS_H);
  float4* PSL = (float4*)(ws + WS_PSL);
  float* partial = (float*)(ws + WS_PART);

  precompute_kernel<<<dim3(N / 4), dim3(256), 0, stream>>>(mu, var, labels, Hf, PSL);
  pair_kernel<<<dim3(NBLK2), dim3(256), 0, stream>>>(Hf, PSL, partial);
  finalize_kernel<<<dim3(1), dim3(256), 0, stream>>>(partial, out);
}